// Round 14
// baseline (777.284 us; speedup 1.0000x reference)
//
#include <hip/hip_runtime.h>

#define N_ 256
#define C_ 2048
#define HW_ 49
#define CPB 64
#define NCC 32          // 64-ch chunks in k_mul / fallback k_main
#define NCHUNK 8        // 256-ch chunks in k_poolc / k_gate2

struct __align__(4) f4a { float x, y, z, w; };   // 4B-aligned 16B load

// ---------------- kernel 1: channel-pool partials, 256 ch per block (r8) ----------------
__global__ __launch_bounds__(256) void k_poolc(const float* __restrict__ x,
                                               float* __restrict__ psum,
                                               float* __restrict__ pmax) {
  const int bc = blockIdx.x, n = blockIdx.y;
  const int t = threadIdx.x;
  __shared__ __align__(16) float sx[CPB * HW_];
  __shared__ float part_s[HW_][5];
  __shared__ float part_m[HW_][5];

  float sm = 0.f, mx = -3.4e38f;
  const int hw = t / 5, s = t % 5;

  const float4* xv = (const float4*)(x + ((size_t)n * C_ + (size_t)bc * 256) * HW_);
  #pragma unroll
  for (int pass = 0; pass < 4; ++pass) {
    float4* sv = (float4*)sx;
    for (int v = t; v < 784; v += 256) sv[v] = xv[pass * 784 + v];
    __syncthreads();
    if (t < 245) {
      #pragma unroll
      for (int j = 0; j < 13; ++j) {
        int c = s * 13 + j;
        if (c < CPB) { float a = sx[c * HW_ + hw]; sm += a; mx = fmaxf(mx, a); }
      }
    }
    __syncthreads();
  }
  if (t < 245) { part_s[hw][s] = sm; part_m[hw][s] = mx; }
  __syncthreads();
  if (t < HW_) {
    float s2 = 0.f, m2 = -3.4e38f;
    #pragma unroll
    for (int k = 0; k < 5; ++k) { s2 += part_s[t][k]; m2 = fmaxf(m2, part_m[t][k]); }
    size_t o = ((size_t)n * NCHUNK + bc) * HW_ + t;
    psum[o] = s2; pmax[o] = m2;
  }
}

// ---------------- kernel 2: per-channel pools from global + dual conv -> gates ----------------
// grid (8, N). Thread t owns channel bc*256+t: 13 direct 16B loads (4B-aligned),
// register pools, 8 b128 pool-row writes, ONE barrier, dual conv (1036 FMA),
// gates straight to global. LDS 34 KB -> 4 blocks/CU.
__device__ __forceinline__ void pool_rows(const float* __restrict__ xp, bool ok,
                                          float* pool_lo, float* pool_hi, int row) {
  float ws[7], wm[7], hs[7], hm[7];
  #pragma unroll
  for (int r = 0; r < 7; ++r) {
    ws[r] = 0.f; hs[r] = 0.f;
    wm[r] = ok ? -3.4e38f : 0.f;     // zero-pad channels contribute 0 in both planes
    hm[r] = ok ? -3.4e38f : 0.f;
  }
  if (ok) {
    #pragma unroll
    for (int b = 0; b < 12; ++b) {   // elements 0..47
      f4a q = *(const f4a*)(xp + b * 4);
      float vv[4] = {q.x, q.y, q.z, q.w};
      #pragma unroll
      for (int j = 0; j < 4; ++j) {
        int e = b * 4 + j;           // compile-time after unroll
        int r = e / 7, k = e % 7;    // static indices -> registers
        ws[r] += vv[j]; wm[r] = fmaxf(wm[r], vv[j]);
        hs[k] += vv[j]; hm[k] = fmaxf(hm[k], vv[j]);
      }
    }
    f4a qt = *(const f4a*)(xp + 45); // element 48 via overlapping tail load (.w)
    ws[6] += qt.w; wm[6] = fmaxf(wm[6], qt.w);
    hs[6] += qt.w; hm[6] = fmaxf(hm[6], qt.w);
  }
  const float C7 = 1.f / 7.f;
  *(float4*)(pool_lo + (0 * 262 + row) * 4) = make_float4(ws[0]*C7, ws[1]*C7, ws[2]*C7, ws[3]*C7);
  *(float4*)(pool_hi + (0 * 262 + row) * 4) = make_float4(ws[4]*C7, ws[5]*C7, ws[6]*C7, 0.f);
  *(float4*)(pool_lo + (1 * 262 + row) * 4) = make_float4(wm[0], wm[1], wm[2], wm[3]);
  *(float4*)(pool_hi + (1 * 262 + row) * 4) = make_float4(wm[4], wm[5], wm[6], 0.f);
  *(float4*)(pool_lo + (2 * 262 + row) * 4) = make_float4(hs[0]*C7, hs[1]*C7, hs[2]*C7, hs[3]*C7);
  *(float4*)(pool_hi + (2 * 262 + row) * 4) = make_float4(hs[4]*C7, hs[5]*C7, hs[6]*C7, 0.f);
  *(float4*)(pool_lo + (3 * 262 + row) * 4) = make_float4(hm[0], hm[1], hm[2], hm[3]);
  *(float4*)(pool_hi + (3 * 262 + row) * 4) = make_float4(hm[4], hm[5], hm[6], 0.f);
}

__global__ __launch_bounds__(256, 4) void k_gate2(const float* __restrict__ x,
    const float* __restrict__ cw, const float* __restrict__ cb,
    const float* __restrict__ bnw, const float* __restrict__ bnb,
    const float* __restrict__ bnrm, const float* __restrict__ bnrv,
    float* __restrict__ gch_g, float* __restrict__ gcw_g) {
  const int bc = blockIdx.x, n = blockIdx.y;
  const int t  = threadIdx.x;

  __shared__ __align__(16) float pool_lo[4 * 262 * 4];  // [f][row][k=0..3]
  __shared__ __align__(16) float pool_hi[4 * 262 * 4];  // [f][row][k=4..6,+pad]
  __shared__ __align__(16) float s_w[112];              // [2][7][8], q-padded

  if (t < 112) {
    int i2w = t / 56, rem = t % 56, p = rem / 8, q = rem % 8;
    s_w[t] = (q < 7) ? cw[i2w * 49 + p * 7 + q] : 0.f;
  }

  // own channel -> pool row t+3
  {
    const float* xp = x + ((size_t)n * C_ + (size_t)bc * 256 + t) * HW_;
    pool_rows(xp, true, pool_lo, pool_hi, t + 3);
  }
  // halo rows 0..2 and 259..261 by threads 0..5
  if (t < 6) {
    int row = (t < 3) ? t : 259 + (t - 3);
    int c = bc * 256 - 3 + row;
    bool ok = (c >= 0 && c < C_);
    const float* xp = x + ((size_t)n * C_ + c) * HW_;
    pool_rows(xp, ok, pool_lo, pool_hi, row);
  }
  __syncthreads();

  // dual conv for channel bc*256+t: rows t..t+6 of all 4 planes
  const float cb0 = cb[0];
  const float sc1 = bnw[1] * rsqrtf(bnrv[1] + 1e-5f), rm1 = bnrm[1], sh1 = bnb[1];
  const float sc2 = bnw[2] * rsqrtf(bnrv[2] + 1e-5f), rm2 = bnrm[2], sh2 = bnb[2];
  float acc0[7] = {0.f, 0.f, 0.f, 0.f, 0.f, 0.f, 0.f};   // g_ch pre-BN
  float acc1[7] = {0.f, 0.f, 0.f, 0.f, 0.f, 0.f, 0.f};   // g_cw pre-BN
  #pragma unroll
  for (int p = 0; p < 7; ++p) {
    float4 wa0 = *(const float4*)(s_w + p * 8);          // i2=0 (mean) weights
    float4 wa1 = *(const float4*)(s_w + p * 8 + 4);
    float4 wb0 = *(const float4*)(s_w + 56 + p * 8);     // i2=1 (max) weights
    float4 wb1 = *(const float4*)(s_w + 56 + p * 8 + 4);
    float wm_[7] = {wa0.x, wa0.y, wa0.z, wa0.w, wa1.x, wa1.y, wa1.z};
    float wx_[7] = {wb0.x, wb0.y, wb0.z, wb0.w, wb1.x, wb1.y, wb1.z};
    int r0 = (0 * 262 + t + p) * 4, r1 = (1 * 262 + t + p) * 4;
    int r2 = (2 * 262 + t + p) * 4, r3 = (3 * 262 + t + p) * 4;
    float4 a_lo = *(const float4*)(pool_lo + r0), a_hi = *(const float4*)(pool_hi + r0);
    float4 b_lo = *(const float4*)(pool_lo + r1), b_hi = *(const float4*)(pool_hi + r1);
    float4 c_lo = *(const float4*)(pool_lo + r2), c_hi = *(const float4*)(pool_hi + r2);
    float4 d_lo = *(const float4*)(pool_lo + r3), d_hi = *(const float4*)(pool_hi + r3);
    float rA[7] = {a_lo.x, a_lo.y, a_lo.z, a_lo.w, a_hi.x, a_hi.y, a_hi.z};
    float rB[7] = {b_lo.x, b_lo.y, b_lo.z, b_lo.w, b_hi.x, b_hi.y, b_hi.z};
    float rC[7] = {c_lo.x, c_lo.y, c_lo.z, c_lo.w, c_hi.x, c_hi.y, c_hi.z};
    float rD[7] = {d_lo.x, d_lo.y, d_lo.z, d_lo.w, d_hi.x, d_hi.y, d_hi.z};
    #pragma unroll
    for (int q = 0; q < 7; ++q) {
      #pragma unroll
      for (int k = 0; k < 7; ++k) {
        int c = k + q - 3;                               // compile-time after unroll
        if (c >= 0 && c < 7) {
          acc0[k] += rA[c] * wm_[q] + rB[c] * wx_[q];
          acc1[k] += rC[c] * wm_[q] + rD[c] * wx_[q];
        }
      }
    }
  }
  // BN + relu + sigmoid, write gates (7 floats per channel per conv)
  float* g1 = gch_g + ((size_t)n * C_ + (size_t)bc * 256 + t) * 7;
  float* g2 = gcw_g + ((size_t)n * C_ + (size_t)bc * 256 + t) * 7;
  #pragma unroll
  for (int k = 0; k < 7; ++k) {
    float y0 = (acc0[k] + cb0 - rm1) * sc1 + sh1;
    y0 = fmaxf(y0, 0.f);
    g1[k] = 1.f / (1.f + __expf(-y0));
    float y1 = (acc1[k] + cb0 - rm2) * sc2 + sh2;
    y1 = fmaxf(y1, 0.f);
    g2[k] = 1.f / (1.f + __expf(-y1));
  }
}

// ---------------- kernel 3: reduce partials, g_hw gate per n ----------------
__global__ __launch_bounds__(64) void k_ghw(const float* __restrict__ psum,
                                            const float* __restrict__ pmax,
                                            const float* __restrict__ cw,
                                            const float* __restrict__ cb,
                                            const float* __restrict__ bnw,
                                            const float* __restrict__ bnb,
                                            const float* __restrict__ bnrm,
                                            const float* __restrict__ bnrv,
                                            float* __restrict__ ghw) {
  const int n = blockIdx.x;
  const int t = threadIdx.x;
  __shared__ float p2c[2][13][13];
  __shared__ float s_cw[98];

  for (int i = t; i < 2 * 13 * 13; i += 64) ((float*)p2c)[i] = 0.f;
  for (int i = t; i < 98; i += 64) s_cw[i] = cw[i];
  __syncthreads();

  if (t < HW_) {
    float sm = 0.f, mx = -3.4e38f;
    const float* ps = psum + (size_t)n * NCHUNK * HW_ + t;
    const float* pm = pmax + (size_t)n * NCHUNK * HW_ + t;
    #pragma unroll
    for (int cc = 0; cc < NCHUNK; ++cc) {
      sm += ps[cc * HW_];
      mx = fmaxf(mx, pm[cc * HW_]);
    }
    p2c[0][t / 7 + 3][t % 7 + 3] = sm * (1.f / C_);
    p2c[1][t / 7 + 3][t % 7 + 3] = mx;
  }
  __syncthreads();

  if (t < HW_) {
    int a = t / 7, b = t % 7;
    float y = cb[0];
    #pragma unroll
    for (int i2 = 0; i2 < 2; ++i2)
      #pragma unroll
      for (int p = 0; p < 7; ++p)
        #pragma unroll
        for (int q = 0; q < 7; ++q)
          y += p2c[i2][a + p][b + q] * s_cw[i2 * 49 + p * 7 + q];
    float sc = bnw[0] * rsqrtf(bnrv[0] + 1e-5f);
    y = (y - bnrm[0]) * sc + bnb[0];
    y = fmaxf(y, 0.f);
    ghw[n * HW_ + t] = 1.f / (1.f + __expf(-y));
  }
}

// ---------------- kernel 4: pure streaming fused multiply (r9, ~13-14 us) ----------------
__global__ __launch_bounds__(256) void k_mul(const float* __restrict__ x,
    const float* __restrict__ ghw, const float* __restrict__ gch_g,
    const float* __restrict__ gcw_g, float* __restrict__ out) {
  const int cc = blockIdx.x;
  const int n  = (N_ - 1) - blockIdx.y;   // reverse n: read freshest L3 lines first
  const int c0 = cc * CPB;
  const int t  = threadIdx.x;

  __shared__ float sg[960];  // [0,448) gch, [448,896) gcw, [896,945) ghw

  {
    const float* g1 = gch_g + ((size_t)n * C_ + c0) * 7;
    const float* g2 = gcw_g + ((size_t)n * C_ + c0) * 7;
    for (int i = t; i < 945; i += 256) {
      float v;
      if (i < 448)      v = g1[i];
      else if (i < 896) v = g2[i - 448];
      else              v = ghw[n * HW_ + (i - 896)];
      sg[i] = v;
    }
  }
  __syncthreads();
  const float* gch = sg;
  const float* gcw = sg + 448;
  const float* s_ghw = sg + 896;

  const float4* xv = (const float4*)(x + ((size_t)n * C_ + c0) * HW_);
  float4* outv = (float4*)(out + ((size_t)n * C_ + c0) * HW_);
  for (int v = t; v < 784; v += 256) {
    float4 q = xv[v];
    int e0 = v * 4;
    int cj = e0 / 49;
    int hw0 = e0 - cj * 49;
    float r[4] = {q.x, q.y, q.z, q.w};
    #pragma unroll
    for (int j = 0; j < 4; ++j) {
      int hw = hw0 + j;
      int cjj = cj + (hw >= 49);
      hw -= (hw >= 49) ? 49 : 0;
      int h = (hw * 37) >> 8, w2 = hw - h * 7;
      r[j] *= (s_ghw[hw] + gch[cjj * 7 + h] + gcw[cjj * 7 + w2]) * (1.f / 3.f);
    }
    outv[v] = make_float4(r[0], r[1], r[2], r[3]);
  }
}

// ============================================================================
// FALLBACK (r13 k_main) — only if ws too small for gates
// ============================================================================
#define CHB(lc) ((lc) * HW_ + ((lc) >= 3 ? 1 : 0))

__global__ __launch_bounds__(256, 6) void k_main_fb(const float* __restrict__ x,
    const float* __restrict__ ghw,
    const float* __restrict__ cw, const float* __restrict__ cb,
    const float* __restrict__ bnw, const float* __restrict__ bnb,
    const float* __restrict__ bnrm, const float* __restrict__ bnrv,
    float* __restrict__ out) {
  const int cc = blockIdx.x;
  const int n  = (N_ - 1) - blockIdx.y;
  const int c0 = cc * CPB;
  const int t  = threadIdx.x;

  __shared__ __align__(16) float sx[3432];
  __shared__ __align__(16) float pool_lo[1120];
  __shared__ __align__(16) float pool_hi[1120];
  __shared__ float gch[448];
  __shared__ float gcw[448];
  __shared__ __align__(16) float s_w[112];
  __shared__ float s_ghw[49];

  const int conv = t & 1, i2 = (t >> 1) & 1, cl = t >> 2;
  const int bi = 1 + conv;
  const float cb0 = cb[0];
  const float sc_bn = bnw[bi] * rsqrtf(bnrv[bi] + 1e-5f);
  const float rm_bn = bnrm[bi];
  const float sh_bn = bnb[bi];

  if (t < 112) {
    int i2w = t / 56, rem = t % 56, p = rem / 8, q = rem % 8;
    s_w[t] = (q < 7) ? cw[i2w * 49 + p * 7 + q] : 0.f;
  }
  if (t < HW_) s_ghw[t] = ghw[n * HW_ + t];
  for (int i = t; i < 2 * 3 * HW_; i += 256) {
    int side = i / 147, off = i % 147;
    int lc = side ? (67 + off / HW_) : (off / HW_);
    int c = c0 - 3 + lc;
    float vv = 0.f;
    if (c >= 0 && c < C_) vv = x[((size_t)n * C_ + c) * HW_ + off % HW_];
    sx[CHB(lc) + off % HW_] = vv;
  }
  const float4* xv = (const float4*)(x + ((size_t)n * C_ + c0) * HW_);
  float4* sxv = (float4*)(sx + 148);
  for (int v = t; v < 784; v += 256) sxv[v] = xv[v];
  __syncthreads();

  for (int i = t; i < 70 * 7; i += 256) {
    int lc = i / 7, k = i % 7;
    int base = CHB(lc);
    float s1 = 0.f, m1 = -3.4e38f, s2 = 0.f, m2 = -3.4e38f;
    #pragma unroll
    for (int j = 0; j < 7; ++j) {
      float a = sx[base + k * 7 + j]; s1 += a; m1 = fmaxf(m1, a);
      float b = sx[base + j * 7 + k]; s2 += b; m2 = fmaxf(m2, b);
    }
    float* pb = (k < 4) ? pool_lo : pool_hi;
    int kk = k & 3;
    pb[(0 * 70 + lc) * 4 + kk] = s1 * (1.f / 7.f);
    pb[(1 * 70 + lc) * 4 + kk] = m1;
    pb[(2 * 70 + lc) * 4 + kk] = s2 * (1.f / 7.f);
    pb[(3 * 70 + lc) * 4 + kk] = m2;
  }
  __syncthreads();

  {
    const int f = conv * 2 + i2;
    const float* Wb = s_w + i2 * 56;
    float acc[7] = {0.f, 0.f, 0.f, 0.f, 0.f, 0.f, 0.f};
    #pragma unroll
    for (int p = 0; p < 7; ++p) {
      int ri = (f * 70 + cl + p) * 4;
      float4 r0 = *(const float4*)(pool_lo + ri);
      float4 r1 = *(const float4*)(pool_hi + ri);
      float row[7] = {r0.x, r0.y, r0.z, r0.w, r1.x, r1.y, r1.z};
      float4 w0 = *(const float4*)(Wb + p * 8);
      float4 w1 = *(const float4*)(Wb + p * 8 + 4);
      float wr[7] = {w0.x, w0.y, w0.z, w0.w, w1.x, w1.y, w1.z};
      #pragma unroll
      for (int q = 0; q < 7; ++q)
        #pragma unroll
        for (int k = 0; k < 7; ++k) {
          int c = k + q - 3;
          if (c >= 0 && c < 7) acc[k] += row[c] * wr[q];
        }
    }
    float fsum[7];
    #pragma unroll
    for (int k = 0; k < 7; ++k) fsum[k] = acc[k] + __shfl_xor(acc[k], 2, 64);
    if (i2 == 0) {
      float* gp = (conv ? gcw : gch) + cl * 7;
      #pragma unroll
      for (int k = 0; k < 7; ++k) {
        float y = (fsum[k] + cb0 - rm_bn) * sc_bn + sh_bn;
        y = fmaxf(y, 0.f);
        gp[k] = 1.f / (1.f + __expf(-y));
      }
    }
  }
  __syncthreads();

  float4* outv = (float4*)(out + ((size_t)n * C_ + c0) * HW_);
  for (int v = t; v < 784; v += 256) {
    float4 q = sxv[v];
    int e0 = v * 4;
    int cj = e0 / 49;
    int hw0 = e0 - cj * 49;
    float r[4] = {q.x, q.y, q.z, q.w};
    #pragma unroll
    for (int j = 0; j < 4; ++j) {
      int hw = hw0 + j;
      int cjj = cj + (hw >= 49);
      hw -= (hw >= 49) ? 49 : 0;
      int h = (hw * 37) >> 8, w2 = hw - h * 7;
      r[j] *= (s_ghw[hw] + gch[cjj * 7 + h] + gcw[cjj * 7 + w2]) * (1.f / 3.f);
    }
    outv[v] = make_float4(r[0], r[1], r[2], r[3]);
  }
}

extern "C" void kernel_launch(void* const* d_in, const int* in_sizes, int n_in,
                              void* d_out, int out_size, void* d_ws, size_t ws_size,
                              hipStream_t stream) {
  const float* x    = (const float*)d_in[0];
  const float* cw   = (const float*)d_in[1];
  const float* cb   = (const float*)d_in[2];
  const float* bnw  = (const float*)d_in[3];
  const float* bnb  = (const float*)d_in[4];
  const float* bnrm = (const float*)d_in[5];
  const float* bnrv = (const float*)d_in[6];
  float* out = (float*)d_out;

  float* psum  = (float*)d_ws;                          // N*8*49
  float* pmax  = psum + (size_t)N_ * NCHUNK * HW_;      // N*8*49
  float* ghw   = pmax + (size_t)N_ * NCHUNK * HW_;      // N*49
  float* gch_g = ghw + (size_t)N_ * HW_;                // N*C*7
  float* gcw_g = gch_g + (size_t)N_ * C_ * 7;           // N*C*7
  size_t need_floats = (size_t)N_ * NCHUNK * HW_ * 2 + (size_t)N_ * HW_
                     + (size_t)N_ * C_ * 7 * 2;

  if (ws_size >= need_floats * sizeof(float)) {
    k_poolc<<<dim3(NCHUNK, N_), 256, 0, stream>>>(x, psum, pmax);
    k_gate2<<<dim3(NCHUNK, N_), 256, 0, stream>>>(x, cw, cb, bnw, bnb, bnrm, bnrv,
                                                  gch_g, gcw_g);
    k_ghw<<<dim3(N_), 64, 0, stream>>>(psum, pmax, cw, cb, bnw, bnb, bnrm, bnrv, ghw);
    k_mul<<<dim3(NCC, N_), 256, 0, stream>>>(x, ghw, gch_g, gcw_g, out);
  } else {
    k_poolc<<<dim3(NCHUNK, N_), 256, 0, stream>>>(x, psum, pmax);
    k_ghw<<<dim3(N_), 64, 0, stream>>>(psum, pmax, cw, cb, bnw, bnb, bnrm, bnrv, ghw);
    k_main_fb<<<dim3(NCC, N_), 256, 0, stream>>>(x, ghw, cw, cb, bnw, bnb, bnrm,
                                                 bnrv, out);
  }
}

// Round 15
// 76.943 us; speedup vs baseline: 10.1020x; 10.1020x over previous
//
#include <hip/hip_runtime.h>

#define N_ 256
#define C_ 2048
#define HW_ 49
#define CPB 64
#define NCHUNK 8        // 256-ch chunks in k_poolc; also tile-groups in k_main_p

// local-channel base in sx: 70 channels (3 halo low, 64 main, 3 halo high).
// Main chunk starts at 148 (16B-aligned for float4); halo-low at 0, gap at 147.
#define CHB(lc) ((lc) * HW_ + ((lc) >= 3 ? 1 : 0))

// ---------------- kernel 1: channel-pool partials, 256 ch per block (r8) ----------------
__global__ __launch_bounds__(256) void k_poolc(const float* __restrict__ x,
                                               float* __restrict__ psum,
                                               float* __restrict__ pmax) {
  const int bc = blockIdx.x, n = blockIdx.y;
  const int t = threadIdx.x;
  __shared__ __align__(16) float sx[CPB * HW_];
  __shared__ float part_s[HW_][5];
  __shared__ float part_m[HW_][5];

  float sm = 0.f, mx = -3.4e38f;
  const int hw = t / 5, s = t % 5;

  const float4* xv = (const float4*)(x + ((size_t)n * C_ + (size_t)bc * 256) * HW_);
  #pragma unroll
  for (int pass = 0; pass < 4; ++pass) {
    float4* sv = (float4*)sx;
    for (int v = t; v < 784; v += 256) sv[v] = xv[pass * 784 + v];
    __syncthreads();
    if (t < 245) {
      #pragma unroll
      for (int j = 0; j < 13; ++j) {
        int c = s * 13 + j;
        if (c < CPB) { float a = sx[c * HW_ + hw]; sm += a; mx = fmaxf(mx, a); }
      }
    }
    __syncthreads();
  }
  if (t < 245) { part_s[hw][s] = sm; part_m[hw][s] = mx; }
  __syncthreads();
  if (t < HW_) {
    float s2 = 0.f, m2 = -3.4e38f;
    #pragma unroll
    for (int k = 0; k < 5; ++k) { s2 += part_s[t][k]; m2 = fmaxf(m2, part_m[t][k]); }
    size_t o = ((size_t)n * NCHUNK + bc) * HW_ + t;
    psum[o] = s2; pmax[o] = m2;
  }
}

// ---------------- kernel 2: reduce chunks, compute g_hw gate per n ----------------
__global__ __launch_bounds__(64) void k_ghw(const float* __restrict__ psum,
                                            const float* __restrict__ pmax,
                                            const float* __restrict__ cw,
                                            const float* __restrict__ cb,
                                            const float* __restrict__ bnw,
                                            const float* __restrict__ bnb,
                                            const float* __restrict__ bnrm,
                                            const float* __restrict__ bnrv,
                                            float* __restrict__ ghw) {
  const int n = blockIdx.x;
  const int t = threadIdx.x;
  __shared__ float p2c[2][13][13];
  __shared__ float s_cw[98];

  for (int i = t; i < 2 * 13 * 13; i += 64) ((float*)p2c)[i] = 0.f;
  for (int i = t; i < 98; i += 64) s_cw[i] = cw[i];
  __syncthreads();

  if (t < HW_) {
    float sm = 0.f, mx = -3.4e38f;
    const float* ps = psum + (size_t)n * NCHUNK * HW_ + t;
    const float* pm = pmax + (size_t)n * NCHUNK * HW_ + t;
    #pragma unroll
    for (int cc = 0; cc < NCHUNK; ++cc) {
      sm += ps[cc * HW_];
      mx = fmaxf(mx, pm[cc * HW_]);
    }
    p2c[0][t / 7 + 3][t % 7 + 3] = sm * (1.f / C_);
    p2c[1][t / 7 + 3][t % 7 + 3] = mx;
  }
  __syncthreads();

  if (t < HW_) {
    int a = t / 7, b = t % 7;
    float y = cb[0];
    #pragma unroll
    for (int i2 = 0; i2 < 2; ++i2)
      #pragma unroll
      for (int p = 0; p < 7; ++p)
        #pragma unroll
        for (int q = 0; q < 7; ++q)
          y += p2c[i2][a + p][b + q] * s_cw[i2 * 49 + p * 7 + q];
    float sc = bnw[0] * rsqrtf(bnrv[0] + 1e-5f);
    y = (y - bnrm[0]) * sc + bnb[0];
    y = fmaxf(y, 0.f);
    ghw[n * HW_ + t] = 1.f / (1.f + __expf(-y));
  }
}

// ---------------- kernel 3: 4-tile pipelined gates + multiply ----------------
// grid (8, N): block owns n and tiles cc = bx*4 .. bx*4+3.
// Per tile: issue next-tile loads (4 float4 + 2 halo floats, uniform guards)
//   -> P1 pools -> bar -> conv (load shadow) -> regs->sx[next] -> bar -> multiply.
// LDS: 2*3432 + 1120 + 1120 + 448 + 448 + 112 + 49 = 10161 fl = 40.6 KB -> 4 blk/CU.
__global__ __launch_bounds__(256, 4) void k_main_p(const float* __restrict__ x,
    const float* __restrict__ ghw,
    const float* __restrict__ cw, const float* __restrict__ cb,
    const float* __restrict__ bnw, const float* __restrict__ bnb,
    const float* __restrict__ bnrm, const float* __restrict__ bnrv,
    float* __restrict__ out) {
  const int bx = blockIdx.x;                  // 0..7
  const int n  = (N_ - 1) - blockIdx.y;       // reverse n: L3-freshest first
  const int t  = threadIdx.x;

  __shared__ __align__(16) float sx[2][3432];
  __shared__ __align__(16) float pool_lo[1120];  // [4][70][4] k=0..3
  __shared__ __align__(16) float pool_hi[1120];  // [4][70][4] k=4..6 (+pad)
  __shared__ float gch[448];
  __shared__ float gcw[448];
  __shared__ __align__(16) float s_w[112];       // [2][7][8] q-padded
  __shared__ float s_ghw[49];

  const int conv = t & 1, i2 = (t >> 1) & 1, cl = t >> 2;
  const int bi = 1 + conv;
  const float cb0 = cb[0];
  const float sc_bn = bnw[bi] * rsqrtf(bnrv[bi] + 1e-5f);
  const float rm_bn = bnrm[bi];
  const float sh_bn = bnb[bi];

  // ---- prologue: params + stage tile 0 into sx[0] ----
  if (t < 112) {
    int i2w = t / 56, rem = t % 56, p = rem / 8, q = rem % 8;
    s_w[t] = (q < 7) ? cw[i2w * 49 + p * 7 + q] : 0.f;
  }
  if (t < HW_) s_ghw[t] = ghw[n * HW_ + t];
  {
    const int c0 = (bx * 4) * CPB;
    for (int i = t; i < 294; i += 256) {        // halo
      int side = i / 147, off = i % 147;
      int lc = side ? (67 + off / HW_) : (off / HW_);
      int c = c0 - 3 + lc;
      float vv = 0.f;
      if (c >= 0 && c < C_) vv = x[((size_t)n * C_ + c) * HW_ + off % HW_];
      sx[0][CHB(lc) + off % HW_] = vv;
    }
    const float4* xv = (const float4*)(x + ((size_t)n * C_ + c0) * HW_);
    float4* sxv = (float4*)(&sx[0][148]);
    for (int v = t; v < 784; v += 256) sxv[v] = xv[v];
  }
  __syncthreads();

  #pragma unroll
  for (int j = 0; j < 4; ++j) {
    const int cur = j & 1, nxt = cur ^ 1;
    const int cc = bx * 4 + j;
    const int c0 = cc * CPB;
    float* sxc = sx[cur];

    // ---- issue next-tile loads (regs live until write below) ----
    float4 q0, q1, q2, q3;
    float h0, h1;
    if (j < 3) {
      const int c0n = (cc + 1) * CPB;
      const float4* xvn = (const float4*)(x + ((size_t)n * C_ + c0n) * HW_);
      if (t < 196) { q0 = xvn[t]; q1 = xvn[t + 196]; q2 = xvn[t + 392]; q3 = xvn[t + 588]; }
      if (t < 147) {
        int lcl = t / 49, off = t % 49;
        int cl_ = c0n - 3 + lcl;            // low-halo channel (always >=0 here, but guard)
        int ch_ = c0n + CPB + lcl;          // high-halo channel
        h0 = (cl_ >= 0 && cl_ < C_) ? x[((size_t)n * C_ + cl_) * HW_ + off] : 0.f;
        h1 = (ch_ < C_) ? x[((size_t)n * C_ + ch_) * HW_ + off] : 0.f;
      }
    }

    // ---- P1: W/H pools for 70 local channels from sx[cur] ----
    for (int i = t; i < 70 * 7; i += 256) {
      int lc = i / 7, k = i % 7;
      int base = CHB(lc);
      float s1 = 0.f, m1 = -3.4e38f, s2 = 0.f, m2 = -3.4e38f;
      #pragma unroll
      for (int jj = 0; jj < 7; ++jj) {
        float a = sxc[base + k * 7 + jj]; s1 += a; m1 = fmaxf(m1, a);  // h=k vary w
        float b = sxc[base + jj * 7 + k]; s2 += b; m2 = fmaxf(m2, b);  // w=k vary h
      }
      float* pb = (k < 4) ? pool_lo : pool_hi;
      int kk = k & 3;
      pb[(0 * 70 + lc) * 4 + kk] = s1 * (1.f / 7.f);
      pb[(1 * 70 + lc) * 4 + kk] = m1;
      pb[(2 * 70 + lc) * 4 + kk] = s2 * (1.f / 7.f);
      pb[(3 * 70 + lc) * 4 + kk] = m2;
    }
    __syncthreads();

    // ---- P2: conv (b128 rows + broadcast weights); thread = (conv,i2,cl) ----
    {
      const int f = conv * 2 + i2;
      const float* Wb = s_w + i2 * 56;
      float acc[7] = {0.f, 0.f, 0.f, 0.f, 0.f, 0.f, 0.f};
      #pragma unroll
      for (int p = 0; p < 7; ++p) {
        int ri = (f * 70 + cl + p) * 4;
        float4 r0 = *(const float4*)(pool_lo + ri);
        float4 r1 = *(const float4*)(pool_hi + ri);
        float row[7] = {r0.x, r0.y, r0.z, r0.w, r1.x, r1.y, r1.z};
        float4 w0 = *(const float4*)(Wb + p * 8);
        float4 w1 = *(const float4*)(Wb + p * 8 + 4);
        float wr[7] = {w0.x, w0.y, w0.z, w0.w, w1.x, w1.y, w1.z};
        #pragma unroll
        for (int q = 0; q < 7; ++q)
          #pragma unroll
          for (int k = 0; k < 7; ++k) {
            int c = k + q - 3;               // compile-time after unroll
            if (c >= 0 && c < 7) acc[k] += row[c] * wr[q];
          }
      }
      float fsum[7];
      #pragma unroll
      for (int k = 0; k < 7; ++k) fsum[k] = acc[k] + __shfl_xor(acc[k], 2, 64);
      if (i2 == 0) {
        float* gp = (conv ? gcw : gch) + cl * 7;
        #pragma unroll
        for (int k = 0; k < 7; ++k) {
          float y = (fsum[k] + cb0 - rm_bn) * sc_bn + sh_bn;
          y = fmaxf(y, 0.f);
          gp[k] = 1.f / (1.f + __expf(-y));
        }
      }
    }

    // ---- write prefetched tile j+1 into sx[nxt] ----
    if (j < 3) {
      float* sxn = sx[nxt];
      float4* sxnv = (float4*)(sxn + 148);
      if (t < 196) { sxnv[t] = q0; sxnv[t + 196] = q1; sxnv[t + 392] = q2; sxnv[t + 588] = q3; }
      if (t < 147) {
        int lcl = t / 49, off = t % 49;
        sxn[CHB(lcl) + off] = h0;
        sxn[CHB(67 + lcl) + off] = h1;
      }
    }
    __syncthreads();

    // ---- P3: fused multiply from sx[cur], float4 stores ----
    {
      const float4* sxv = (const float4*)(sxc + 148);
      float4* outv = (float4*)(out + ((size_t)n * C_ + c0) * HW_);
      for (int v = t; v < 784; v += 256) {
        float4 q = sxv[v];
        int e0 = v * 4;
        int cj = e0 / 49;
        int hw0 = e0 - cj * 49;
        float r[4] = {q.x, q.y, q.z, q.w};
        #pragma unroll
        for (int jj = 0; jj < 4; ++jj) {
          int hw = hw0 + jj;
          int cjj = cj + (hw >= 49);
          hw -= (hw >= 49) ? 49 : 0;
          int h = (hw * 37) >> 8, w2 = hw - h * 7;
          r[jj] *= (s_ghw[hw] + gch[cjj * 7 + h] + gcw[cjj * 7 + w2]) * (1.f / 3.f);
        }
        outv[v] = make_float4(r[0], r[1], r[2], r[3]);
      }
    }
    // no 3rd barrier: next P1 writes pools / reads sx[nxt] (disjoint from P3's
    // reads of sx[cur]/gch/gcw); next conv's gch writes are fenced by next bar1.
  }
}

extern "C" void kernel_launch(void* const* d_in, const int* in_sizes, int n_in,
                              void* d_out, int out_size, void* d_ws, size_t ws_size,
                              hipStream_t stream) {
  const float* x    = (const float*)d_in[0];
  const float* cw   = (const float*)d_in[1];
  const float* cb   = (const float*)d_in[2];
  const float* bnw  = (const float*)d_in[3];
  const float* bnb  = (const float*)d_in[4];
  const float* bnrm = (const float*)d_in[5];
  const float* bnrv = (const float*)d_in[6];
  float* out = (float*)d_out;

  float* psum = (float*)d_ws;                         // N*8*49
  float* pmax = psum + (size_t)N_ * NCHUNK * HW_;     // N*8*49
  float* ghw  = pmax + (size_t)N_ * NCHUNK * HW_;     // N*49

  k_poolc<<<dim3(NCHUNK, N_), 256, 0, stream>>>(x, psum, pmax);
  k_ghw<<<dim3(N_), 64, 0, stream>>>(psum, pmax, cw, cb, bnw, bnb, bnrm, bnrv, ghw);
  k_main_p<<<dim3(NCHUNK, N_), 256, 0, stream>>>(x, ghw, cw, cb, bnw, bnb, bnrm,
                                                 bnrv, out);
}